// Round 10
// baseline (524.115 us; speedup 1.0000x reference)
//
#include <hip/hip_runtime.h>

// TrendGRU R10: 32x32x16 MFMA, C = W*h, with (1) K-permutation so each
// lane's B-fragment = its OWN C-layout h dwords (no shfl/LDS exchange at
// all), and (2) 4-way batched reciprocals (72 -> 45 trans/wave-t; trans
// issue measured at 53% of cycles in R9).
// pi (unit -> k) : k0-7 = units {0-3,8-11} (half0-owned), k8-15 = {4-7,
// 12-15} (half1-owned), k16-19 = {16-19}, k20/21 = bias hi/lo (const-1
// multiplier), k24-27 = {20-23}, k28/29 = x_hi/x_lo (Wih_hi), k30 = x_hi
// (Wih_lo), rest 0. So B0 = [P0,P1], B1 = [P2, c2, c3] with c2/c3 the only
// half-dependent dwords (bias-consts vs x-pack).
// W hi/lo split (fp32 recovery); r,z pre-scaled by log2(e), n by 2*log2(e);
// n-gate x-term as exact fp32 fma in epilogue. 12 MFMA_32 per wave-t.
// Batched rcp: inv of 4 denoms via 1 v_rcp + product tree; sigmoid denoms
// <= 2^14 (4-prod 2^56, safe); tanh exp2-args clamped at 30 (4-prod 2^120,
// clamp error ~2e-9). 1024 blocks x 1 wave; LDS only in the FC head.

#define GRU_T 512
#define FS 28   // FC LDS row stride in floats (head only)

typedef __attribute__((ext_vector_type(8)))  short bf16x8;
typedef __attribute__((ext_vector_type(16))) float f32x16;

__device__ __forceinline__ float bf16hi_f(float v) {   // RNE-to-bf16, as float
    unsigned u = __float_as_uint(v);
    u = (u + 0x7FFFu + ((u >> 16) & 1u)) & 0xFFFF0000u;
    return __uint_as_float(u);
}
__device__ __forceinline__ unsigned bf16_rne(float v) {
    unsigned u = __float_as_uint(v);
    return (u + 0x7FFFu + ((u >> 16) & 1u)) >> 16;
}
__device__ __forceinline__ f32x16 mfma32(bf16x8 a, bf16x8 b, f32x16 c) {
    return __builtin_amdgcn_mfma_f32_32x32x16_bf16(a, b, c, 0, 0, 0);
}
// 1/d[i] for 4 positive denominators with ONE v_rcp (product tree).
__device__ __forceinline__ void inv4(const float d0, const float d1,
                                     const float d2, const float d3,
                                     float* i0, float* i1, float* i2, float* i3) {
    const float p01 = d0 * d1, p23 = d2 * d3;
    const float r   = __builtin_amdgcn_rcpf(p01 * p23);
    const float r01 = r * p23, r23 = r * p01;
    *i0 = r01 * d1; *i1 = r01 * d0;
    *i2 = r23 * d3; *i3 = r23 * d2;
}

__global__ __launch_bounds__(64) void trend_gru_r10(
    const float* __restrict__ x,     // (B, T)
    const float* __restrict__ W_ih,  // (72,)
    const float* __restrict__ b_ih,  // (72,)
    const float* __restrict__ W_hh,  // (72, 24) rows r,z,n
    const float* __restrict__ b_hh,  // (72,)
    const float* __restrict__ fc_w,  // (2, 24)
    const float* __restrict__ fc_b,  // (2,)
    float* __restrict__ out)         // (B, 2)
{
    const int lane = threadIdx.x;
    const int e    = lane & 31;          // element (B/C column)
    const int half = lane >> 5;
    const int elem0 = blockIdx.x * 32;

    __shared__ __align__(16) float Flds[32 * FS];   // FC head only

    const float L2E = 1.4426950408889634f;

    // k-slot codes: 0-23 = h-unit; 24 = b_hi (x const 1); 25 = b_lo;
    // 26,27 = Wih_hi (x_hi, x_lo); 28 = Wih_lo (x_hi); 29 = zero.
    const int pi[32] = { 0, 1, 2, 3, 8, 9,10,11,
                         4, 5, 6, 7,12,13,14,15,
                        16,17,18,19,24,25,29,29,
                        20,21,22,23,26,27,28,29};

    // ---- A fragments (weights), built once ----
    // A layout: row m = lane&31 (= gate unit), k = kstep*16 + half*8 + jj.
    bf16x8 A[3][2][2];
#pragma unroll
    for (int g = 0; g < 3; ++g) {
        const float sc = (g == 2) ? 2.0f * L2E : L2E;
        const int m = e;
        const bool valid = m < 24;
        const int R = g * 24 + (valid ? m : 0);
        const float wx = (g < 2 && valid) ? sc * W_ih[R] : 0.0f;
        const float bb = valid ? sc * ((g < 2) ? (b_ih[R] + b_hh[R]) : b_hh[R]) : 0.0f;
        const float wxh = bf16hi_f(wx), bbh = bf16hi_f(bb);
#pragma unroll
        for (int s = 0; s < 2; ++s) {
            bf16x8 fh, fl;
#pragma unroll
            for (int jj = 0; jj < 8; ++jj) {
                const int k = s * 16 + half * 8 + jj;
                const int c = pi[k];
                float vh = 0.0f, vl = 0.0f;
                if (valid) {
                    if (c < 24) {
                        const float w  = sc * W_hh[R * 24 + c];
                        const float wh = bf16hi_f(w);
                        vh = wh; vl = w - wh;
                    } else if (c == 24) {
                        vh = bbh;
                    } else if (c == 25) {
                        vh = bb - bbh;
                    } else if (c == 26 || c == 27) {
                        vh = wxh;
                    } else if (c == 28) {
                        vh = wx - wxh;
                    }
                }
                fh[jj] = (short)bf16_rne(vh);
                fl[jj] = (short)bf16_rne(vl);
            }
            A[g][s][0] = fh;
            A[g][s][1] = fl;
        }
    }

    // ---- per-lane n-gate x-path constants (exact fp32) ----
    // C-layout slot s (0..11) -> unit j = (s&3) + 8*(s>>2) + 4*half
    float wn_s[12], bn_s[12];
#pragma unroll
    for (int s = 0; s < 12; ++s) {
        const int j = (s & 3) + 8 * (s >> 2) + 4 * half;
        wn_s[s] = 2.0f * L2E * W_ih[48 + j];
        bn_s[s] = 2.0f * L2E * b_ih[48 + j];
    }

    const float* xp = x + (size_t)(elem0 + e) * GRU_T;
    float xv = xp[0];

    float h[12];
#pragma unroll
    for (int s = 0; s < 12; ++s) h[s] = 0.0f;

    // packed h dwords: P[G][i] = units (8G + 4*half) + {2i, 2i+1}
    unsigned P[3][2];
#pragma unroll
    for (int G = 0; G < 3; ++G) { P[G][0] = 0u; P[G][1] = 0u; }

    const f32x16 z16 = {0.f,0.f,0.f,0.f,0.f,0.f,0.f,0.f,
                        0.f,0.f,0.f,0.f,0.f,0.f,0.f,0.f};

#pragma unroll 1
    for (int t = 0; t < GRU_T; ++t) {
        // half-dependent B1 tail dwords: half0 = bias consts, half1 = x-pack
        const unsigned uhi = bf16_rne(xv);
        const float    xh  = __uint_as_float(uhi << 16);
        const unsigned ulo = bf16_rne(xv - xh);
        const unsigned c2  = half ? (uhi | (ulo << 16)) : 0x3F803F80u;  // k20/21=1,1 | k28/29=xh,xl
        const unsigned c3  = half ? uhi : 0u;                           // k30=xh (Wlo), k31=0

        uint4 b0v, b1v;
        b0v.x = P[0][0]; b0v.y = P[0][1]; b0v.z = P[1][0]; b0v.w = P[1][1];
        b1v.x = P[2][0]; b1v.y = P[2][1]; b1v.z = c2;      b1v.w = c3;
        const bf16x8 B0 = *(const bf16x8*)&b0v;
        const bf16x8 B1 = *(const bf16x8*)&b1v;

        const float xnext = xp[(t + 1 < GRU_T) ? t + 1 : t];

        f32x16 aR = mfma32(A[0][0][0], B0, z16);
        aR = mfma32(A[0][0][1], B0, aR);
        aR = mfma32(A[0][1][0], B1, aR);
        aR = mfma32(A[0][1][1], B1, aR);
        f32x16 aZ = mfma32(A[1][0][0], B0, z16);
        aZ = mfma32(A[1][0][1], B0, aZ);
        aZ = mfma32(A[1][1][0], B1, aZ);
        aZ = mfma32(A[1][1][1], B1, aZ);
        f32x16 aN = mfma32(A[2][0][0], B0, z16);
        aN = mfma32(A[2][0][1], B0, aN);
        aN = mfma32(A[2][1][0], B1, aN);
        aN = mfma32(A[2][1][1], B1, aN);

        // epilogue: acc regs 0..11 (12..15 = pad units, statically skipped)
#pragma unroll
        for (int G = 0; G < 3; ++G) {
            float dR[4], dZ[4], axv[4];
#pragma unroll
            for (int q = 0; q < 4; ++q) {
                const int s = G * 4 + q;
                dR[q]  = 1.0f + __builtin_amdgcn_exp2f(-aR[s]);
                dZ[q]  = 1.0f + __builtin_amdgcn_exp2f(-aZ[s]);
                axv[q] = fmaf(wn_s[s], xv, bn_s[s]);
            }
            float iR[4], iZ[4];
            inv4(dR[0], dR[1], dR[2], dR[3], &iR[0], &iR[1], &iR[2], &iR[3]);
            inv4(dZ[0], dZ[1], dZ[2], dZ[3], &iZ[0], &iZ[1], &iZ[2], &iZ[3]);

            float dN[4];
#pragma unroll
            for (int q = 0; q < 4; ++q) {
                const int s = G * 4 + q;
                float np = fmaf(iR[q], aN[s], axv[q]);
                np = fminf(np, 30.0f);   // tanh saturated; keeps 4-prod < 2^127
                dN[q] = 1.0f + __builtin_amdgcn_exp2f(np);
            }
            float iN[4];
            inv4(dN[0], dN[1], dN[2], dN[3], &iN[0], &iN[1], &iN[2], &iN[3]);

            unsigned u4[4];
#pragma unroll
            for (int q = 0; q < 4; ++q) {
                const int s = G * 4 + q;
                const float nn = fmaf(-2.0f, iN[q], 1.0f);
                const float hn = fmaf(iZ[q], h[s] - nn, nn);
                h[s] = hn;
                unsigned u = __float_as_uint(hn);
                u4[q] = u + 0x7FFFu + ((u >> 16) & 1u);
            }
            // perm(a=HIGH,b=LOW): 0x07060302 -> [bf16(q0) | bf16(q1)<<16]
            P[G][0] = __builtin_amdgcn_perm(u4[1], u4[0], 0x07060302u);
            P[G][1] = __builtin_amdgcn_perm(u4[3], u4[2], 0x07060302u);
        }
        xv = xnext;
    }

    // ---- FC head: h (fp32) -> LDS, lanes 0..31 reduce 24 -> 2 ----
#pragma unroll
    for (int G = 0; G < 3; ++G) {
        float4 f4;
        f4.x = h[G * 4 + 0]; f4.y = h[G * 4 + 1];
        f4.z = h[G * 4 + 2]; f4.w = h[G * 4 + 3];
        *(float4*)(&Flds[e * FS + G * 8 + half * 4]) = f4;
    }
    __builtin_amdgcn_s_waitcnt(0);   // lgkmcnt(0): same-wave LDS visibility
    if (lane < 32) {
        float o0 = fc_b[0], o1 = fc_b[1];
#pragma unroll
        for (int j = 0; j < 24; ++j) {
            const float hv = Flds[lane * FS + j];
            o0 = fmaf(hv, fc_w[j],      o0);
            o1 = fmaf(hv, fc_w[24 + j], o1);
        }
        float2 o; o.x = o0; o.y = o1;
        *(float2*)(out + (size_t)(elem0 + lane) * 2) = o;
    }
}

extern "C" void kernel_launch(void* const* d_in, const int* in_sizes, int n_in,
                              void* d_out, int out_size, void* d_ws, size_t ws_size,
                              hipStream_t stream) {
    const float* x    = (const float*)d_in[0];
    const float* W_ih = (const float*)d_in[1];
    const float* b_ih = (const float*)d_in[2];
    const float* W_hh = (const float*)d_in[3];
    const float* b_hh = (const float*)d_in[4];
    const float* fc_w = (const float*)d_in[5];
    const float* fc_b = (const float*)d_in[6];
    float* out = (float*)d_out;

    const int B = in_sizes[0] / GRU_T;      // 32768
    const int grid = B / 32;                // 1024 blocks x 1 wave
    trend_gru_r10<<<grid, 64, 0, stream>>>(x, W_ih, b_ih, W_hh, b_hh,
                                           fc_w, fc_b, out);
}

// Round 11
// 511.702 us; speedup vs baseline: 1.0243x; 1.0243x over previous
//
#include <hip/hip_runtime.h>

// TrendGRU R11: 32x32x16 MFMA, C = W*h, K-permuted B (lane's B-fragment =
// its OWN C-layout h dwords; no shfl/LDS exchange), with a chain-neutral
// trans reduction: per-slot shared z-n reciprocal.
//   h' = n + (h-n)/Dz,  n = 1 - 2/Dn  ->  inv = rcp(Dz*Dn), iZ = inv*Dn,
//   iN = inv*Dz.  5 trans/slot (3 exp2 + 2 rcp), 12 INDEPENDENT slot
// chains (R5/R10 showed batching trades issue for ILP and loses at
// 1 wave/SIMD). Overflow-safe: Dz<=2^14, Dn<=2^19 -> product << 2^127.
// pi (unit -> k): k0-7 = units {0-3,8-11}, k8-15 = {4-7,12-15},
// k16-19 = {16-19}, k20/21 = bias hi/lo, k24-27 = {20-23}, k28/29 =
// x_hi/x_lo (Wih_hi), k30 = x_hi (Wih_lo). B0 = [P0,P1], B1 = [P2,c2,c3].
// W hi/lo split (fp32 recovery); r,z pre-scaled by log2(e), n by 2*log2(e);
// n-gate x-term as exact fp32 fma. 12 MFMA_32/wave-t; LDS only in FC head.

#define GRU_T 512
#define FS 28   // FC LDS row stride in floats (head only)

typedef __attribute__((ext_vector_type(8)))  short bf16x8;
typedef __attribute__((ext_vector_type(16))) float f32x16;

__device__ __forceinline__ float bf16hi_f(float v) {   // RNE-to-bf16, as float
    unsigned u = __float_as_uint(v);
    u = (u + 0x7FFFu + ((u >> 16) & 1u)) & 0xFFFF0000u;
    return __uint_as_float(u);
}
__device__ __forceinline__ unsigned bf16_rne(float v) {
    unsigned u = __float_as_uint(v);
    return (u + 0x7FFFu + ((u >> 16) & 1u)) >> 16;
}
__device__ __forceinline__ f32x16 mfma32(bf16x8 a, bf16x8 b, f32x16 c) {
    return __builtin_amdgcn_mfma_f32_32x32x16_bf16(a, b, c, 0, 0, 0);
}

__global__ __launch_bounds__(64) void trend_gru_r11(
    const float* __restrict__ x,     // (B, T)
    const float* __restrict__ W_ih,  // (72,)
    const float* __restrict__ b_ih,  // (72,)
    const float* __restrict__ W_hh,  // (72, 24) rows r,z,n
    const float* __restrict__ b_hh,  // (72,)
    const float* __restrict__ fc_w,  // (2, 24)
    const float* __restrict__ fc_b,  // (2,)
    float* __restrict__ out)         // (B, 2)
{
    const int lane = threadIdx.x;
    const int e    = lane & 31;          // element (B/C column)
    const int half = lane >> 5;
    const int elem0 = blockIdx.x * 32;

    __shared__ __align__(16) float Flds[32 * FS];   // FC head only

    const float L2E = 1.4426950408889634f;

    // k-slot codes: 0-23 = h-unit; 24 = b_hi (const-1); 25 = b_lo;
    // 26,27 = Wih_hi (x_hi, x_lo); 28 = Wih_lo (x_hi); 29 = zero.
    const int pi[32] = { 0, 1, 2, 3, 8, 9,10,11,
                         4, 5, 6, 7,12,13,14,15,
                        16,17,18,19,24,25,29,29,
                        20,21,22,23,26,27,28,29};

    // ---- A fragments (weights), built once ----
    // A layout: row m = lane&31 (= gate unit), k = kstep*16 + half*8 + jj.
    bf16x8 A[3][2][2];
#pragma unroll
    for (int g = 0; g < 3; ++g) {
        const float sc = (g == 2) ? 2.0f * L2E : L2E;
        const int m = e;
        const bool valid = m < 24;
        const int R = g * 24 + (valid ? m : 0);
        const float wx = (g < 2 && valid) ? sc * W_ih[R] : 0.0f;
        const float bb = valid ? sc * ((g < 2) ? (b_ih[R] + b_hh[R]) : b_hh[R]) : 0.0f;
        const float wxh = bf16hi_f(wx), bbh = bf16hi_f(bb);
#pragma unroll
        for (int s = 0; s < 2; ++s) {
            bf16x8 fh, fl;
#pragma unroll
            for (int jj = 0; jj < 8; ++jj) {
                const int k = s * 16 + half * 8 + jj;
                const int c = pi[k];
                float vh = 0.0f, vl = 0.0f;
                if (valid) {
                    if (c < 24) {
                        const float w  = sc * W_hh[R * 24 + c];
                        const float wh = bf16hi_f(w);
                        vh = wh; vl = w - wh;
                    } else if (c == 24) {
                        vh = bbh;
                    } else if (c == 25) {
                        vh = bb - bbh;
                    } else if (c == 26 || c == 27) {
                        vh = wxh;
                    } else if (c == 28) {
                        vh = wx - wxh;
                    }
                }
                fh[jj] = (short)bf16_rne(vh);
                fl[jj] = (short)bf16_rne(vl);
            }
            A[g][s][0] = fh;
            A[g][s][1] = fl;
        }
    }

    // ---- per-lane n-gate x-path constants (exact fp32) ----
    // C-layout slot s (0..11) -> unit j = (s&3) + 8*(s>>2) + 4*half
    float wn_s[12], bn_s[12];
#pragma unroll
    for (int s = 0; s < 12; ++s) {
        const int j = (s & 3) + 8 * (s >> 2) + 4 * half;
        wn_s[s] = 2.0f * L2E * W_ih[48 + j];
        bn_s[s] = 2.0f * L2E * b_ih[48 + j];
    }

    const float* xp = x + (size_t)(elem0 + e) * GRU_T;
    float xv = xp[0];

    float h[12];
#pragma unroll
    for (int s = 0; s < 12; ++s) h[s] = 0.0f;

    // packed h dwords: P[G][i] = units (8G + 4*half) + {2i, 2i+1}
    unsigned P[3][2];
#pragma unroll
    for (int G = 0; G < 3; ++G) { P[G][0] = 0u; P[G][1] = 0u; }

    const f32x16 z16 = {0.f,0.f,0.f,0.f,0.f,0.f,0.f,0.f,
                        0.f,0.f,0.f,0.f,0.f,0.f,0.f,0.f};

#pragma unroll 1
    for (int t = 0; t < GRU_T; ++t) {
        // half-dependent B1 tail dwords: half0 = bias consts, half1 = x-pack
        const unsigned uhi = bf16_rne(xv);
        const float    xh  = __uint_as_float(uhi << 16);
        const unsigned ulo = bf16_rne(xv - xh);
        const unsigned c2  = half ? (uhi | (ulo << 16)) : 0x3F803F80u;
        const unsigned c3  = half ? uhi : 0u;

        uint4 b0v, b1v;
        b0v.x = P[0][0]; b0v.y = P[0][1]; b0v.z = P[1][0]; b0v.w = P[1][1];
        b1v.x = P[2][0]; b1v.y = P[2][1]; b1v.z = c2;      b1v.w = c3;
        const bf16x8 B0 = *(const bf16x8*)&b0v;
        const bf16x8 B1 = *(const bf16x8*)&b1v;

        const float xnext = xp[(t + 1 < GRU_T) ? t + 1 : t];

        f32x16 aR = mfma32(A[0][0][0], B0, z16);
        aR = mfma32(A[0][0][1], B0, aR);
        aR = mfma32(A[0][1][0], B1, aR);
        aR = mfma32(A[0][1][1], B1, aR);
        f32x16 aZ = mfma32(A[1][0][0], B0, z16);
        aZ = mfma32(A[1][0][1], B0, aZ);
        aZ = mfma32(A[1][1][0], B1, aZ);
        aZ = mfma32(A[1][1][1], B1, aZ);
        f32x16 aN = mfma32(A[2][0][0], B0, z16);
        aN = mfma32(A[2][0][1], B0, aN);
        aN = mfma32(A[2][1][0], B1, aN);
        aN = mfma32(A[2][1][1], B1, aN);

        // epilogue: 12 INDEPENDENT slot chains, 5 trans each
        // (shared z-n rcp: h' = n + (h-n)/Dz, n = 1-2/Dn)
#pragma unroll
        for (int G = 0; G < 3; ++G) {
            unsigned u4[4];
#pragma unroll
            for (int q = 0; q < 4; ++q) {
                const int s = G * 4 + q;
                const float eR = __builtin_amdgcn_exp2f(-aR[s]);
                const float iR = __builtin_amdgcn_rcpf(1.0f + eR);
                const float ax = fmaf(wn_s[s], xv, bn_s[s]);
                const float np = fmaf(iR, aN[s], ax);
                const float eN = __builtin_amdgcn_exp2f(np);
                const float eZ = __builtin_amdgcn_exp2f(-aZ[s]);
                const float DN = 1.0f + eN;
                const float DZ = 1.0f + eZ;
                const float inv = __builtin_amdgcn_rcpf(DZ * DN);
                const float iZ = inv * DN;      // 1/DZ
                const float iN = inv * DZ;      // 1/DN
                const float nn = fmaf(-2.0f, iN, 1.0f);
                const float hn = fmaf(iZ, h[s] - nn, nn);
                h[s] = hn;
                unsigned u = __float_as_uint(hn);
                u4[q] = u + 0x7FFFu + ((u >> 16) & 1u);
            }
            // perm(a=HIGH,b=LOW): 0x07060302 -> [bf16(q0) | bf16(q1)<<16]
            P[G][0] = __builtin_amdgcn_perm(u4[1], u4[0], 0x07060302u);
            P[G][1] = __builtin_amdgcn_perm(u4[3], u4[2], 0x07060302u);
        }
        xv = xnext;
    }

    // ---- FC head: h (fp32) -> LDS, lanes 0..31 reduce 24 -> 2 ----
#pragma unroll
    for (int G = 0; G < 3; ++G) {
        float4 f4;
        f4.x = h[G * 4 + 0]; f4.y = h[G * 4 + 1];
        f4.z = h[G * 4 + 2]; f4.w = h[G * 4 + 3];
        *(float4*)(&Flds[e * FS + G * 8 + half * 4]) = f4;
    }
    __builtin_amdgcn_s_waitcnt(0);   // lgkmcnt(0): same-wave LDS visibility
    if (lane < 32) {
        float o0 = fc_b[0], o1 = fc_b[1];
#pragma unroll
        for (int j = 0; j < 24; ++j) {
            const float hv = Flds[lane * FS + j];
            o0 = fmaf(hv, fc_w[j],      o0);
            o1 = fmaf(hv, fc_w[24 + j], o1);
        }
        float2 o; o.x = o0; o.y = o1;
        *(float2*)(out + (size_t)(elem0 + lane) * 2) = o;
    }
}

extern "C" void kernel_launch(void* const* d_in, const int* in_sizes, int n_in,
                              void* d_out, int out_size, void* d_ws, size_t ws_size,
                              hipStream_t stream) {
    const float* x    = (const float*)d_in[0];
    const float* W_ih = (const float*)d_in[1];
    const float* b_ih = (const float*)d_in[2];
    const float* W_hh = (const float*)d_in[3];
    const float* b_hh = (const float*)d_in[4];
    const float* fc_w = (const float*)d_in[5];
    const float* fc_b = (const float*)d_in[6];
    float* out = (float*)d_out;

    const int B = in_sizes[0] / GRU_T;      // 32768
    const int grid = B / 32;                // 1024 blocks x 1 wave
    trend_gru_r11<<<grid, 64, 0, stream>>>(x, W_ih, b_ih, W_hh, b_hh,
                                           fc_w, fc_b, out);
}